// Round 13
// baseline (805.949 us; speedup 1.0000x reference)
//
#include <hip/hip_runtime.h>
#include <hip/hip_bf16.h>
#include <stdint.h>

typedef unsigned long long u64;
typedef unsigned int u32;
typedef __attribute__((ext_vector_type(8))) short bf16x8;
typedef __attribute__((ext_vector_type(8))) unsigned short u16x8;
typedef __attribute__((ext_vector_type(4))) float f32x4;

__device__ __forceinline__ float ldv(const void* p, size_t idx, int mode) {
  return mode ? __bfloat162float(((const __hip_bfloat16*)p)[idx])
              : ((const float*)p)[idx];
}
__device__ __forceinline__ void stv(void* p, size_t idx, int mode, float v) {
  if (mode) ((__hip_bfloat16*)p)[idx] = __float2bfloat16(v);
  else      ((float*)p)[idx] = v;
}
__device__ __forceinline__ unsigned short f2bfb(float f) {  // RNE f32->bf16 bits
  u32 u = __float_as_uint(f);
  u32 r = u + 0x7fffu + ((u >> 16) & 1u);
  return (unsigned short)(r >> 16);
}
__device__ __forceinline__ float bfb2f(unsigned short b) {
  return __uint_as_float((u32)b << 16);
}
__device__ __forceinline__ u64 shfl64(u64 v, int src) {
  int lo = __shfl((int)(u32)(v & 0xffffffffu), src, 64);
  int hi = __shfl((int)(u32)(v >> 32), src, 64);
  return ((u64)(u32)hi << 32) | (u32)lo;
}
__device__ __forceinline__ u64 shflxor64(u64 v, int m) {
  int lo = __shfl_xor((int)(u32)(v & 0xffffffffu), m, 64);
  int hi = __shfl_xor((int)(u32)(v >> 32), m, 64);
  return ((u64)(u32)hi << 32) | (u32)lo;
}
__device__ __forceinline__ u64 shfl64w16(u64 v, int src) {  // width-16 shfl
  int lo = __shfl((int)(u32)(v & 0xffffffffu), src, 16);
  int hi = __shfl((int)(u32)(v >> 32), src, 16);
  return ((u64)(u32)hi << 32) | (u32)lo;
}

__global__ void PointNetSimple_61409442398998_kernel() {}

// ------------------------------- grid params -------------------------------
#define GRD 64
#define GRD3 (GRD*GRD*GRD)
#define GLO (-4.75f)
#define GH 0.1484375f          // 9.5/64, exact
#define GINVH 6.7368421053f    // 64/9.5

__device__ __forceinline__ int cell_of(float x, float y, float z,
                                       int& gx, int& gy, int& gz) {
  gx = min(GRD-1, max(0, (int)floorf((x - GLO) * GINVH)));
  gy = min(GRD-1, max(0, (int)floorf((y - GLO) * GINVH)));
  gz = min(GRD-1, max(0, (int)floorf((z - GLO) * GINVH)));
  return (gz*GRD + gy)*GRD + gx;
}

// ---------------------------------------------------------------------------
// setup: dtype-detect + weight transpose/convert + vector cvt + prep
// (pos4/h0) + grid histogram (cellId, atomicAdd cellCnt).
// ---------------------------------------------------------------------------
struct CvtEnt { const void* src; float* dst; int n; };
struct CvtArgs { CvtEnt e[12]; };
struct WEnt { const void* src; unsigned short* dst; int K, N, Kpad; };
struct WArgs { WEnt e[6]; };

__global__ void zero_kernel(u32* __restrict__ p) {   // 262144 u32, grid 256x256
  int i = blockIdx.x * blockDim.x + threadIdx.x;
  ((uint4*)p)[i] = make_uint4(0u, 0u, 0u, 0u);
}

__global__ void setup_kernel(const void* __restrict__ pos,
                             const void* __restrict__ nrm,
                             WArgs wa, CvtArgs ca,
                             int* __restrict__ flag,
                             float4* __restrict__ pos4,
                             float* __restrict__ h0,
                             u32* __restrict__ cellId,
                             u32* __restrict__ cellCnt, int n) {
  const unsigned short* u16p = (const unsigned short*)pos;
  int cnt = 0;
  for (int k = 0; k < 32; ++k) {
    int e = (u16p[k] >> 7) & 0xff;
    if (e >= 110 && e <= 140) cnt++;
  }
  const int mode = (cnt >= 26) ? 1 : 0;

  const int nprep = n >> 8;
  const int b = blockIdx.x;
  if (b < nprep) {
    int i = b * 256 + threadIdx.x;
    float x = ldv(pos, 3*(size_t)i+0, mode);
    float y = ldv(pos, 3*(size_t)i+1, mode);
    float z = ldv(pos, 3*(size_t)i+2, mode);
    pos4[i] = make_float4(x, y, z, x*x + y*y + z*z);
    h0[6*(size_t)i+0] = x; h0[6*(size_t)i+1] = y; h0[6*(size_t)i+2] = z;
    h0[6*(size_t)i+3] = ldv(nrm, 3*(size_t)i+0, mode);
    h0[6*(size_t)i+4] = ldv(nrm, 3*(size_t)i+1, mode);
    h0[6*(size_t)i+5] = ldv(nrm, 3*(size_t)i+2, mode);
    int gx, gy, gz;
    int cid = cell_of(x, y, z, gx, gy, gz);
    cellId[i] = (u32)cid;
    atomicAdd(&cellCnt[cid], 1u);
  } else {
    int r = b - nprep;
    if (r < 6) {
      WEnt ent = wa.e[r];
      for (int t = threadIdx.x; t < ent.N * ent.Kpad; t += blockDim.x) {
        int nn = t / ent.Kpad;
        int k  = t - nn * ent.Kpad;
        float v = (k < ent.K) ? ldv(ent.src, (size_t)k * ent.N + nn, mode) : 0.0f;
        ent.dst[t] = f2bfb(v);
      }
      if (r == 0 && threadIdx.x == 0) flag[0] = mode;
    } else {
      for (int t2 = 0; t2 < 12; ++t2) {
        CvtEnt ent = ca.e[t2];
        for (int t = threadIdx.x; t < ent.n; t += blockDim.x)
          ent.dst[t] = ldv(ent.src, t, mode);
      }
    }
  }
}

// ---- two-level exclusive scan over 262144 cell counts ----
__global__ __launch_bounds__(256) void scanA_kernel(const u32* __restrict__ cnt,
                                                    u32* __restrict__ off,
                                                    u32* __restrict__ blkSum) {
  __shared__ u32 s[256];
  const int b = blockIdx.x, t = threadIdx.x;
  const int base = b*1024 + t*4;
  u32 c0 = cnt[base], c1 = cnt[base+1], c2 = cnt[base+2], c3 = cnt[base+3];
  u32 sum = c0+c1+c2+c3;
  s[t] = sum;
  __syncthreads();
  u32 v = sum;
  for (int d = 1; d < 256; d <<= 1) {
    u32 o = (t >= d) ? s[t-d] : 0u;
    __syncthreads();
    v += o; s[t] = v;
    __syncthreads();
  }
  u32 excl = v - sum;
  off[base]   = excl;
  off[base+1] = excl + c0;
  off[base+2] = excl + c0 + c1;
  off[base+3] = excl + c0 + c1 + c2;
  if (t == 255) blkSum[b] = v;
}

__global__ void scanB_kernel(u32* __restrict__ blkSum) {   // 1 block x 256
  __shared__ u32 s[256];
  const int t = threadIdx.x;
  u32 x = blkSum[t]; s[t] = x; __syncthreads();
  u32 v = x;
  for (int d = 1; d < 256; d <<= 1) {
    u32 o = (t >= d) ? s[t-d] : 0u;
    __syncthreads();
    v += o; s[t] = v;
    __syncthreads();
  }
  blkSum[t] = v - x;
}

__global__ void scatter_kernel(const u32* __restrict__ cellId,
                               u32* __restrict__ cellOff,
                               const u32* __restrict__ blkScan,
                               u32* __restrict__ ptIdx, int n) {
  int i = blockIdx.x * blockDim.x + threadIdx.x;
  if (i >= n) return;
  u32 c = cellId[i];
  u32 slot = atomicAdd(&cellOff[c], 1u);            // local slot (off = local start)
  ptIdx[blkScan[c >> 10] + slot] = (u32)i;
}

// ---------------------------------------------------------------------------
// knn grid query: wave-per-target, Chebyshev ring expansion. Candidates feed
// the PROVEN ballot/mbcnt append + bitonic flush (u64 keys = d2_bits<<32|j =
// exact lax.top_k order). Stop when ((r-1)*h)^2 > th + 1e-4 (geometric lower
// bound for all unexamined cells + fp-error margin => examined set is a
// superset of the true top-16; clamped outliers remain conservative since
// they lie beyond their cell in the outward direction). d2 VERBATIM (frozen).
// ---------------------------------------------------------------------------
#define KNN_WPB 8

__device__ __forceinline__ void knn_flush(u64* __restrict__ wbuf, int& cnt,
                                          u64& val, u64& t15, float& th,
                                          int lane) {
  u64 cand = (lane < cnt) ? wbuf[lane] : ~0ull;
#pragma unroll
  for (int k = 2; k <= 64; k <<= 1) {
#pragma unroll
    for (int j = k >> 1; j > 0; j >>= 1) {
      u64 other = shflxor64(cand, j);
      bool up    = ((lane & k) == 0) || (k == 64);
      bool lower = ((lane & j) == 0);
      bool keepMin = (up == lower);
      u64 mn = cand < other ? cand : other;
      u64 mx = cand < other ? other : cand;
      cand = keepMin ? mn : mx;
    }
  }
  u64 rev = shfl64w16(cand, 15 - (lane & 15));
  u64 lo = val < rev ? val : rev;
#pragma unroll
  for (int j = 8; j > 0; j >>= 1) {
    u64 other = shflxor64(lo, j);
    bool lower = ((lane & j) == 0);
    u64 mn = lo < other ? lo : other;
    u64 mx = lo < other ? other : lo;
    lo = lower ? mn : mx;
  }
  val = (lane < 16) ? lo : ~0ull;
  t15 = shfl64(val, 15);
  if (t15 != ~0ull) th = __uint_as_float((u32)(t15 >> 32));  // NaN guard (<16 seen)
  cnt = 0;
}

__global__ __launch_bounds__(512) void knng_kernel(
    const float4* __restrict__ pos4,
    const u32* __restrict__ cellCnt,
    const u32* __restrict__ cellOff,
    const u32* __restrict__ blkScan,
    const u32* __restrict__ ptIdx,
    int* __restrict__ nbr, int n) {
  __shared__ u64 buf[KNN_WPB][72];
  const int tid = threadIdx.x, lane = tid & 63, wid = tid >> 6;
  const int i = blockIdx.x * KNN_WPB + wid;
  const float4 pi = pos4[i];
  u64* wbuf = &buf[wid][0];

  u64 val = ~0ull, t15 = ~0ull;
  float th = 3.4e38f;
  int cnt = 0;

  int gx, gy, gz;
  cell_of(pi.x, pi.y, pi.z, gx, gy, gz);

  for (int r = 0; r < GRD; ++r) {
    if (r >= 1 && t15 != ~0ull) {
      float bound = (float)(r - 1) * GH;
      if (bound * bound > th + 1e-4f) break;
    }
    const int S = 2*r + 1;
    const int S2 = S*S;
    const int S3 = S2*S;
    for (int l0 = 0; l0 < S3; l0 += 64) {
      int l = l0 + lane;
      int myCnt = 0; u32 myStart = 0;
      if (l < S3) {
        int dz = l / S2;
        int rem = l - dz*S2;
        int dy = rem / S;
        int dx = rem - dy*S;
        dx -= r; dy -= r; dz -= r;
        int cheb = max(abs(dx), max(abs(dy), abs(dz)));
        int cx = gx + dx, cy = gy + dy, cz = gz + dz;
        if (cheb == r && cx >= 0 && cx < GRD && cy >= 0 && cy < GRD &&
            cz >= 0 && cz < GRD) {
          int c = (cz*GRD + cy)*GRD + cx;
          myCnt = (int)cellCnt[c];
          myStart = blkScan[c >> 10] + cellOff[c] - (u32)myCnt;
        }
      }
      for (int k = 0; ; ++k) {
        bool has = (k < myCnt);
        if (__ballot(has) == 0ull) break;
        float d2 = 3.4e38f; u32 j = 0xffffffffu;
        if (has) {
          j = ptIdx[myStart + k];
          float4 a = pos4[j];
          float dd = (pi.w + a.w) - 2.0f*(pi.x*a.x + pi.y*a.y + pi.z*a.z);
          d2 = fmaxf(dd, 0.0f);
        }
        bool pass = has && (d2 <= th);
        u64 bal = __ballot(pass);
        if (bal) {
          int pc = __popcll(bal);
          if (cnt + pc > 64) knn_flush(wbuf, cnt, val, t15, th, lane);
          u32 mb = __builtin_amdgcn_mbcnt_lo((u32)bal, 0u);
          mb = __builtin_amdgcn_mbcnt_hi((u32)(bal >> 32), mb);
          if (pass)
            wbuf[cnt + mb] = ((u64)__float_as_uint(d2) << 32) | j;
          cnt += pc;
        }
      }
    }
    knn_flush(wbuf, cnt, val, t15, th, lane);   // tighten th for stop check
  }
  if (lane < 16) nbr[(size_t)i*16 + lane] = (int)(val & 0xffffffffu);
}

// ---------------------------------------------------------------------------
// MFMA conv v4: as v3 (zero-sync, per-wave bands, bf16 GN stage) but
// activations flow as bf16 ws rows (bit-identical to v3's fp32->f2bfb path,
// half the gather bytes).
// ---------------------------------------------------------------------------
template<int CIN, int CMID, int KT1, int NT, int KT2>
__global__ __launch_bounds__(256, 4) void conv_mfma4_kernel(
    const float* __restrict__ xf,             // [N,6] fp32 (CIN==6)
    const unsigned short* __restrict__ xb,    // [N,64] bf16 (CIN==64)
    const float4* __restrict__ pos4,
    const int* __restrict__ nbr,
    const int* __restrict__ flag,
    const unsigned short* __restrict__ WaT,   // [CMID][K1PAD] bf16
    const unsigned short* __restrict__ WbT,   // [CMID][CMID]  bf16
    const float* __restrict__ baf,
    const float* __restrict__ gmf,
    const float* __restrict__ btf,
    const float* __restrict__ bbf,
    unsigned short* __restrict__ xoutb,       // [N,CMID] bf16 ws (may be null)
    void* __restrict__ bout, size_t out_off)
{
  constexpr int K1PAD = KT1 * 32;
  constexpr int SB = CMID + 8;

  __shared__ unsigned short msgB[128 * SB];
  __shared__ __align__(16) unsigned short stageb[4][32][24];

  const int tid  = threadIdx.x;
  const int lane = tid & 63;
  const int w    = tid >> 6;
  const int quad = lane >> 4;
  const int cl   = lane & 15;
  const int node0 = blockIdx.x * 8;
  const int mode = flag[0];

  bf16x8 afr[2][KT1];
#pragma unroll
  for (int mt = 0; mt < 2; ++mt) {
    const int node = node0 + w*2 + mt;
    const int j = nbr[(size_t)node*16 + cl];
    const float4 pin = pos4[node];
    const float4 pj = pos4[j];
    const float rx = pj.x - pin.x, ry = pj.y - pin.y, rz = pj.z - pin.z;
    if constexpr (CIN == 64) {
#pragma unroll
      for (int kt = 0; kt < 2; ++kt)
        afr[mt][kt] = *(const bf16x8*)&xb[(size_t)j*64 + kt*32 + quad*8];
      unsigned short o[8] = {0,0,0,0,0,0,0,0};
      if (quad == 0) { o[0] = f2bfb(rx); o[1] = f2bfb(ry); o[2] = f2bfb(rz); }
      afr[mt][KT1-1] = *(bf16x8*)o;
    } else {  // CIN == 6
      unsigned short o[8] = {0,0,0,0,0,0,0,0};
      if (quad == 0) {
        const float* p = &xf[(size_t)j*6];
        o[0] = f2bfb(p[0]); o[1] = f2bfb(p[1]); o[2] = f2bfb(p[2]);
        o[3] = f2bfb(p[3]); o[4] = f2bfb(p[4]); o[5] = f2bfb(p[5]);
        o[6] = f2bfb(rx);   o[7] = f2bfb(ry);
      } else if (quad == 1) {
        o[0] = f2bfb(rz);
      }
      afr[mt][0] = *(bf16x8*)o;
    }
  }

  f32x4 acc1[2][NT];
#pragma unroll
  for (int mt = 0; mt < 2; ++mt)
#pragma unroll
    for (int nt = 0; nt < NT; ++nt) acc1[mt][nt] = (f32x4){0.f, 0.f, 0.f, 0.f};
#pragma unroll
  for (int kt = 0; kt < KT1; ++kt)
#pragma unroll
    for (int nt = 0; nt < NT; ++nt) {
      bf16x8 bfr = *(const bf16x8*)&WaT[(size_t)(nt*16 + cl) * K1PAD + kt*32 + quad*8];
      acc1[0][nt] = __builtin_amdgcn_mfma_f32_16x16x32_bf16(afr[0][kt], bfr, acc1[0][nt], 0, 0, 0);
      acc1[1][nt] = __builtin_amdgcn_mfma_f32_16x16x32_bf16(afr[1][kt], bfr, acc1[1][nt], 0, 0, 0);
    }

#pragma unroll
  for (int nt = 0; nt < NT; ++nt) {
    float bac = baf[nt*16 + cl];
#pragma unroll
    for (int mt = 0; mt < 2; ++mt)
#pragma unroll
      for (int reg = 0; reg < 4; ++reg)
        stageb[w][mt*16 + quad*4 + reg][cl] = f2bfb(acc1[mt][nt][reg] + bac);
    asm volatile("" ::: "memory");
    {
      int row = lane >> 1, gl = lane & 1;
      u16x8 hv = *(const u16x8*)&stageb[w][row][gl*8];
      float vv[8];
#pragma unroll
      for (int e = 0; e < 8; ++e) vv[e] = bfb2f(hv[e]);
      float s = 0.f, q = 0.f;
#pragma unroll
      for (int e = 0; e < 8; ++e) { s += vv[e]; q += vv[e]*vv[e]; }
      float mu = s * 0.125f;
      float var = q * 0.125f - mu * mu;
      float inv = rsqrtf(fmaxf(var, 0.0f) + 1e-5f);
      int cb = nt*16 + gl*8;
      unsigned short o[8];
#pragma unroll
      for (int e = 0; e < 8; ++e) {
        float t = (vv[e] - mu) * inv * gmf[cb+e] + btf[cb+e];
        o[e] = f2bfb(fmaxf(t, 0.0f));
      }
      *(bf16x8*)&msgB[(w*32 + row) * SB + cb] = *(bf16x8*)o;
    }
    asm volatile("" ::: "memory");
  }

  f32x4 acc2[2][NT];
#pragma unroll
  for (int mt = 0; mt < 2; ++mt)
#pragma unroll
    for (int nt = 0; nt < NT; ++nt) acc2[mt][nt] = (f32x4){0.f, 0.f, 0.f, 0.f};
#pragma unroll
  for (int kt = 0; kt < KT2; ++kt) {
    bf16x8 af0 = *(const bf16x8*)&msgB[(w*32 + cl)      * SB + kt*32 + quad*8];
    bf16x8 af1 = *(const bf16x8*)&msgB[(w*32 + 16 + cl) * SB + kt*32 + quad*8];
#pragma unroll
    for (int nt = 0; nt < NT; ++nt) {
      bf16x8 bfr = *(const bf16x8*)&WbT[(size_t)(nt*16 + cl) * CMID + kt*32 + quad*8];
      acc2[0][nt] = __builtin_amdgcn_mfma_f32_16x16x32_bf16(af0, bfr, acc2[0][nt], 0, 0, 0);
      acc2[1][nt] = __builtin_amdgcn_mfma_f32_16x16x32_bf16(af1, bfr, acc2[1][nt], 0, 0, 0);
    }
  }

#pragma unroll
  for (int mt = 0; mt < 2; ++mt) {
    int node = node0 + w*2 + mt;
#pragma unroll
    for (int nt = 0; nt < NT; ++nt) {
      float m = fmaxf(fmaxf(acc2[mt][nt][0], acc2[mt][nt][1]),
                      fmaxf(acc2[mt][nt][2], acc2[mt][nt][3]));
      m = fmaxf(m, __shfl_xor(m, 16, 64));
      m = fmaxf(m, __shfl_xor(m, 32, 64));
      float v = fmaxf(m + bbf[nt*16 + cl], 0.0f);
      if (quad == 0) {
        size_t oi = (size_t)node * CMID + nt*16 + cl;
        if (xoutb) xoutb[oi] = f2bfb(v);
        stv(bout, out_off + oi, mode, v);
      }
    }
  }
}

// ---------------------------------------------------------------------------
extern "C" void kernel_launch(void* const* d_in, const int* in_sizes, int n_in,
                              void* d_out, int out_size, void* d_ws, size_t ws_size,
                              hipStream_t stream) {
  (void)n_in; (void)ws_size; (void)in_sizes;
  int n = out_size / 256;
  if (n <= 0 || (n & 255)) n = 16384;

  // ws layout (float slots):
  float* ws = (float*)d_ws;
  int*    flag    = (int*)ws;                                  // 16
  float4* pos4    = (float4*)(ws + 16);                        // 4n
  float*  h0      = ws + 16 + (size_t)4*n;                     // 6n
  int*    nbr     = (int*)(ws + 16 + (size_t)10*n);            // 16n
  unsigned short* h1b = (unsigned short*)(ws + 16 + (size_t)26*n);  // 32n
  unsigned short* h2b = (unsigned short*)(ws + 16 + (size_t)58*n);  // 32n
  float*  vbuf    = ws + 16 + (size_t)90*n;                    // 1024
  unsigned short* wtbuf = (unsigned short*)(vbuf + 1024);      // 22528 slots
  u32*    cellCnt = (u32*)(ws + 16 + (size_t)90*n + 23552);    // 262144
  u32*    cellOff = cellCnt + GRD3;                            // 262144
  u32*    blkScan = cellOff + GRD3;                            // 512
  u32*    cellId  = blkScan + 512;                             // n
  u32*    ptIdx   = cellId + n;                                // n

  const int vsz[12] = {64,64,64,64, 64,64,64,64, 128,128,128,128};
  const int vsrc[12] = {3,4,5,7, 9,10,11,13, 15,16,17,19};
  CvtArgs ca;
  float* vptr[12];
  {
    int off = 0;
    for (int t = 0; t < 12; ++t) {
      ca.e[t].src = d_in[vsrc[t]];
      ca.e[t].dst = vbuf + off;
      ca.e[t].n   = vsz[t];
      vptr[t] = vbuf + off;
      off += vsz[t];
    }
  }
  const int wK[6]    = {9, 64, 67, 64, 67, 128};
  const int wN[6]    = {64, 64, 64, 64, 128, 128};
  const int wKp[6]   = {32, 64, 96, 64, 96, 128};
  const int wsrc[6]  = {2, 6, 8, 12, 14, 18};
  WArgs wa;
  unsigned short* wptr[6];
  {
    int off = 0;
    for (int t = 0; t < 6; ++t) {
      wa.e[t].src  = d_in[wsrc[t]];
      wa.e[t].dst  = wtbuf + off;
      wa.e[t].K    = wK[t];
      wa.e[t].N    = wN[t];
      wa.e[t].Kpad = wKp[t];
      wptr[t] = wtbuf + off;
      off += wN[t] * wKp[t];
    }
  }

  zero_kernel<<<GRD3/4/256, 256, 0, stream>>>(cellCnt);
  setup_kernel<<<n/256 + 7, 256, 0, stream>>>(
      d_in[0], d_in[1], wa, ca, flag, pos4, h0, cellId, cellCnt, n);
  scanA_kernel<<<256, 256, 0, stream>>>(cellCnt, cellOff, blkScan);
  scanB_kernel<<<1, 256, 0, stream>>>(blkScan);
  scatter_kernel<<<n/256, 256, 0, stream>>>(cellId, cellOff, blkScan, ptIdx, n);
  knng_kernel<<<n/KNN_WPB, 512, 0, stream>>>(
      pos4, cellCnt, cellOff, blkScan, ptIdx, nbr, n);

  // <CIN, CMID, KT1, NT, KT2>
  conv_mfma4_kernel<6, 64, 1, 4, 2><<<n/8, 256, 0, stream>>>(
      h0, (const unsigned short*)nullptr, pos4, nbr, flag, wptr[0], wptr[1],
      vptr[0], vptr[1], vptr[2], vptr[3], h1b, d_out, (size_t)0);
  conv_mfma4_kernel<64, 64, 3, 4, 2><<<n/8, 256, 0, stream>>>(
      (const float*)nullptr, h1b, pos4, nbr, flag, wptr[2], wptr[3],
      vptr[4], vptr[5], vptr[6], vptr[7], h2b, d_out, (size_t)n*64);
  conv_mfma4_kernel<64, 128, 3, 8, 4><<<n/8, 256, 0, stream>>>(
      (const float*)nullptr, h2b, pos4, nbr, flag, wptr[4], wptr[5],
      vptr[8], vptr[9], vptr[10], vptr[11],
      (unsigned short*)nullptr, d_out, (size_t)n*128);
}

// Round 14
// 371.679 us; speedup vs baseline: 2.1684x; 2.1684x over previous
//
#include <hip/hip_runtime.h>
#include <hip/hip_bf16.h>
#include <stdint.h>

typedef unsigned long long u64;
typedef unsigned int u32;
typedef __attribute__((ext_vector_type(8))) short bf16x8;
typedef __attribute__((ext_vector_type(8))) unsigned short u16x8;
typedef __attribute__((ext_vector_type(4))) float f32x4;

__device__ __forceinline__ float ldv(const void* p, size_t idx, int mode) {
  return mode ? __bfloat162float(((const __hip_bfloat16*)p)[idx])
              : ((const float*)p)[idx];
}
__device__ __forceinline__ void stv(void* p, size_t idx, int mode, float v) {
  if (mode) ((__hip_bfloat16*)p)[idx] = __float2bfloat16(v);
  else      ((float*)p)[idx] = v;
}
__device__ __forceinline__ unsigned short f2bfb(float f) {  // RNE f32->bf16 bits
  u32 u = __float_as_uint(f);
  u32 r = u + 0x7fffu + ((u >> 16) & 1u);
  return (unsigned short)(r >> 16);
}
__device__ __forceinline__ float bfb2f(unsigned short b) {
  return __uint_as_float((u32)b << 16);
}
__device__ __forceinline__ u64 shfl64(u64 v, int src) {
  int lo = __shfl((int)(u32)(v & 0xffffffffu), src, 64);
  int hi = __shfl((int)(u32)(v >> 32), src, 64);
  return ((u64)(u32)hi << 32) | (u32)lo;
}
__device__ __forceinline__ u64 shflxor64(u64 v, int m) {
  int lo = __shfl_xor((int)(u32)(v & 0xffffffffu), m, 64);
  int hi = __shfl_xor((int)(u32)(v >> 32), m, 64);
  return ((u64)(u32)hi << 32) | (u32)lo;
}
__device__ __forceinline__ u64 shfl64w16(u64 v, int src) {  // width-16 shfl
  int lo = __shfl((int)(u32)(v & 0xffffffffu), src, 16);
  int hi = __shfl((int)(u32)(v >> 32), src, 16);
  return ((u64)(u32)hi << 32) | (u32)lo;
}

__global__ void PointNetSimple_61409442398998_kernel() {}

// ---------------------------------------------------------------------------
// setup: dtype-detect + weight transpose/convert + vector cvt + prep.
// ---------------------------------------------------------------------------
struct CvtEnt { const void* src; float* dst; int n; };
struct CvtArgs { CvtEnt e[12]; };
struct WEnt { const void* src; unsigned short* dst; int K, N, Kpad; };
struct WArgs { WEnt e[6]; };

__global__ void setup_kernel(const void* __restrict__ pos,
                             const void* __restrict__ nrm,
                             WArgs wa, CvtArgs ca,
                             int* __restrict__ flag,
                             float4* __restrict__ pos4,
                             float* __restrict__ h0, int n) {
  const unsigned short* u16p = (const unsigned short*)pos;
  int cnt = 0;
  for (int k = 0; k < 32; ++k) {
    int e = (u16p[k] >> 7) & 0xff;
    if (e >= 110 && e <= 140) cnt++;
  }
  const int mode = (cnt >= 26) ? 1 : 0;

  const int nprep = n >> 8;
  const int b = blockIdx.x;
  if (b < nprep) {
    int i = b * 256 + threadIdx.x;
    float x = ldv(pos, 3*(size_t)i+0, mode);
    float y = ldv(pos, 3*(size_t)i+1, mode);
    float z = ldv(pos, 3*(size_t)i+2, mode);
    pos4[i] = make_float4(x, y, z, x*x + y*y + z*z);
    h0[6*(size_t)i+0] = x; h0[6*(size_t)i+1] = y; h0[6*(size_t)i+2] = z;
    h0[6*(size_t)i+3] = ldv(nrm, 3*(size_t)i+0, mode);
    h0[6*(size_t)i+4] = ldv(nrm, 3*(size_t)i+1, mode);
    h0[6*(size_t)i+5] = ldv(nrm, 3*(size_t)i+2, mode);
  } else {
    int r = b - nprep;
    if (r < 6) {
      WEnt ent = wa.e[r];
      for (int t = threadIdx.x; t < ent.N * ent.Kpad; t += blockDim.x) {
        int nn = t / ent.Kpad;
        int k  = t - nn * ent.Kpad;
        float v = (k < ent.K) ? ldv(ent.src, (size_t)k * ent.N + nn, mode) : 0.0f;
        ent.dst[t] = f2bfb(v);
      }
      if (r == 0 && threadIdx.x == 0) flag[0] = mode;
    } else {
      for (int t2 = 0; t2 < 12; ++t2) {
        CvtEnt ent = ca.e[t2];
        for (int t = threadIdx.x; t < ent.n; t += blockDim.x)
          ent.dst[t] = ldv(ent.src, t, mode);
      }
    }
  }
}

// ---------------------------------------------------------------------------
// knn v4 (proven 168 us): wave-per-target, streaming LDS chunks, mbcnt
// compaction + exact bitonic flush. u64 keys = exact lax.top_k order.
// d2 expression verbatim (boundary-rounding frozen).
// ---------------------------------------------------------------------------
#define KNN_TPB 512
#define KNN_WPB 8
#define KCH 1024

__device__ __forceinline__ void knn_flush(u64* __restrict__ wbuf, int& cnt,
                                          u64& val, u64& t15, float& th,
                                          int lane) {
  u64 cand = (lane < cnt) ? wbuf[lane] : ~0ull;
#pragma unroll
  for (int k = 2; k <= 64; k <<= 1) {
#pragma unroll
    for (int j = k >> 1; j > 0; j >>= 1) {
      u64 other = shflxor64(cand, j);
      bool up    = ((lane & k) == 0) || (k == 64);
      bool lower = ((lane & j) == 0);
      bool keepMin = (up == lower);
      u64 mn = cand < other ? cand : other;
      u64 mx = cand < other ? other : cand;
      cand = keepMin ? mn : mx;
    }
  }
  u64 rev = shfl64w16(cand, 15 - (lane & 15));
  u64 lo = val < rev ? val : rev;
#pragma unroll
  for (int j = 8; j > 0; j >>= 1) {
    u64 other = shflxor64(lo, j);
    bool lower = ((lane & j) == 0);
    u64 mn = lo < other ? lo : other;
    u64 mx = lo < other ? other : lo;
    lo = lower ? mn : mx;
  }
  val = (lane < 16) ? lo : ~0ull;
  t15 = shfl64(val, 15);
  th = __uint_as_float((u32)(t15 >> 32));
  cnt = 0;
}

__global__ __launch_bounds__(KNN_TPB) void knn4_kernel(
    const float4* __restrict__ pos4, int* __restrict__ nbr, int n) {
  __shared__ float4 sp[2][KCH];
  __shared__ u64 buf[KNN_WPB][72];
  const int tid  = threadIdx.x;
  const int lane = tid & 63;
  const int wid  = tid >> 6;
  const int i    = blockIdx.x * KNN_WPB + wid;
  const float4 pi = pos4[i];
  u64* wbuf = &buf[wid][0];

  u64 val = ~0ull;
  u64 t15 = ~0ull;
  float th = 3.4e38f;
  int cnt = 0;

  for (int t = tid; t < KCH; t += KNN_TPB) sp[0][t] = pos4[t];
  __syncthreads();

  const int nch = n / KCH;
  for (int c = 0; c < nch; ++c) {
    const int cur = c & 1;
    float4 pre0, pre1;
    const bool more = (c + 1 < nch);
    if (more) {
      pre0 = pos4[(size_t)(c+1)*KCH + tid];
      pre1 = pos4[(size_t)(c+1)*KCH + KNN_TPB + tid];
    }
#pragma unroll 2
    for (int t = 0; t < KCH; t += 64) {
      float4 a = sp[cur][t + lane];
      float d2 = (pi.w + a.w) - 2.0f*(pi.x*a.x + pi.y*a.y + pi.z*a.z);
      d2 = fmaxf(d2, 0.0f);
      bool pass = (d2 <= th);
      u64 bal = __ballot(pass);
      if (bal) {
        int pc = __popcll(bal);
        if (cnt + pc > 64) knn_flush(wbuf, cnt, val, t15, th, lane);
        u32 mb = __builtin_amdgcn_mbcnt_lo((u32)bal, 0u);
        mb = __builtin_amdgcn_mbcnt_hi((u32)(bal >> 32), mb);
        if (pass)
          wbuf[cnt + mb] = ((u64)__float_as_uint(d2) << 32) | (u32)(c*KCH + t + lane);
        cnt += pc;
      }
    }
    if (more) {
      sp[cur^1][tid] = pre0;
      sp[cur^1][KNN_TPB + tid] = pre1;
    }
    __syncthreads();
  }
  knn_flush(wbuf, cnt, val, t15, th, lane);
  if (lane < 16) nbr[(size_t)i*16 + lane] = (int)(val & 0xffffffffu);
}

// ---------------------------------------------------------------------------
// MFMA conv v5: zero-sync, per-wave bands, bf16 activations. GN restructure:
// phase A writes ALL raw (acc+bias) tiles bf16 IN PLACE into msgB; ONE fence;
// phase B normalizes each tile in place (independent b128 read->stats->write,
// reads overlap). Replaces NT serialized LDS round-trips with 1. stageb
// deleted (conv1/2 LDS 24.6->18.4 KB). Numerics: identical quantize-before-
// stats as v3/v4 -> absmax expected bit-identical (0.0246582).
// ---------------------------------------------------------------------------
template<int CIN, int CMID, int KT1, int NT, int KT2>
__global__ __launch_bounds__(256, 4) void conv_mfma5_kernel(
    const float* __restrict__ xf,             // [N,6] fp32 (CIN==6)
    const unsigned short* __restrict__ xb,    // [N,64] bf16 (CIN==64)
    const float4* __restrict__ pos4,
    const int* __restrict__ nbr,
    const int* __restrict__ flag,
    const unsigned short* __restrict__ WaT,   // [CMID][K1PAD] bf16
    const unsigned short* __restrict__ WbT,   // [CMID][CMID]  bf16
    const float* __restrict__ baf,
    const float* __restrict__ gmf,
    const float* __restrict__ btf,
    const float* __restrict__ bbf,
    unsigned short* __restrict__ xoutb,       // [N,CMID] bf16 ws (may be null)
    void* __restrict__ bout, size_t out_off)
{
  constexpr int K1PAD = KT1 * 32;
  constexpr int SB = CMID + 8;

  __shared__ unsigned short msgB[128 * SB];

  const int tid  = threadIdx.x;
  const int lane = tid & 63;
  const int w    = tid >> 6;
  const int quad = lane >> 4;
  const int cl   = lane & 15;
  const int node0 = blockIdx.x * 8;
  const int mode = flag[0];

  bf16x8 afr[2][KT1];
#pragma unroll
  for (int mt = 0; mt < 2; ++mt) {
    const int node = node0 + w*2 + mt;
    const int j = nbr[(size_t)node*16 + cl];
    const float4 pin = pos4[node];
    const float4 pj = pos4[j];
    const float rx = pj.x - pin.x, ry = pj.y - pin.y, rz = pj.z - pin.z;
    if constexpr (CIN == 64) {
#pragma unroll
      for (int kt = 0; kt < 2; ++kt)
        afr[mt][kt] = *(const bf16x8*)&xb[(size_t)j*64 + kt*32 + quad*8];
      unsigned short o[8] = {0,0,0,0,0,0,0,0};
      if (quad == 0) { o[0] = f2bfb(rx); o[1] = f2bfb(ry); o[2] = f2bfb(rz); }
      afr[mt][KT1-1] = *(bf16x8*)o;
    } else {  // CIN == 6
      unsigned short o[8] = {0,0,0,0,0,0,0,0};
      if (quad == 0) {
        const float* p = &xf[(size_t)j*6];
        o[0] = f2bfb(p[0]); o[1] = f2bfb(p[1]); o[2] = f2bfb(p[2]);
        o[3] = f2bfb(p[3]); o[4] = f2bfb(p[4]); o[5] = f2bfb(p[5]);
        o[6] = f2bfb(rx);   o[7] = f2bfb(ry);
      } else if (quad == 1) {
        o[0] = f2bfb(rz);
      }
      afr[mt][0] = *(bf16x8*)o;
    }
  }

  f32x4 acc1[2][NT];
#pragma unroll
  for (int mt = 0; mt < 2; ++mt)
#pragma unroll
    for (int nt = 0; nt < NT; ++nt) acc1[mt][nt] = (f32x4){0.f, 0.f, 0.f, 0.f};
#pragma unroll
  for (int kt = 0; kt < KT1; ++kt)
#pragma unroll
    for (int nt = 0; nt < NT; ++nt) {
      bf16x8 bfr = *(const bf16x8*)&WaT[(size_t)(nt*16 + cl) * K1PAD + kt*32 + quad*8];
      acc1[0][nt] = __builtin_amdgcn_mfma_f32_16x16x32_bf16(afr[0][kt], bfr, acc1[0][nt], 0, 0, 0);
      acc1[1][nt] = __builtin_amdgcn_mfma_f32_16x16x32_bf16(afr[1][kt], bfr, acc1[1][nt], 0, 0, 0);
    }

  // ---- phase A: raw acc+bias -> msgB in place (bf16), ALL tiles ----
#pragma unroll
  for (int nt = 0; nt < NT; ++nt) {
    float bac = baf[nt*16 + cl];
#pragma unroll
    for (int mt = 0; mt < 2; ++mt)
#pragma unroll
      for (int reg = 0; reg < 4; ++reg)
        msgB[(w*32 + mt*16 + quad*4 + reg) * SB + nt*16 + cl] =
            f2bfb(acc1[mt][nt][reg] + bac);
  }
  asm volatile("" ::: "memory");   // per-wave DS FIFO orders phase A before B

  // ---- phase B: GroupNorm(8)+ReLU in place, independent per tile ----
  {
    const int row = lane >> 1, gl = lane & 1;
#pragma unroll
    for (int nt = 0; nt < NT; ++nt) {
      const int cb = nt*16 + gl*8;
      unsigned short* p = &msgB[(w*32 + row) * SB + cb];
      u16x8 hv = *(const u16x8*)p;
      float vv[8];
#pragma unroll
      for (int e = 0; e < 8; ++e) vv[e] = bfb2f(hv[e]);
      float s = 0.f, q = 0.f;
#pragma unroll
      for (int e = 0; e < 8; ++e) { s += vv[e]; q += vv[e]*vv[e]; }
      float mu = s * 0.125f;
      float var = q * 0.125f - mu * mu;
      float inv = rsqrtf(fmaxf(var, 0.0f) + 1e-5f);
      unsigned short o[8];
#pragma unroll
      for (int e = 0; e < 8; ++e) {
        float t = (vv[e] - mu) * inv * gmf[cb+e] + btf[cb+e];
        o[e] = f2bfb(fmaxf(t, 0.0f));
      }
      *(bf16x8*)p = *(bf16x8*)o;
    }
  }
  asm volatile("" ::: "memory");

  f32x4 acc2[2][NT];
#pragma unroll
  for (int mt = 0; mt < 2; ++mt)
#pragma unroll
    for (int nt = 0; nt < NT; ++nt) acc2[mt][nt] = (f32x4){0.f, 0.f, 0.f, 0.f};
#pragma unroll
  for (int kt = 0; kt < KT2; ++kt) {
    bf16x8 af0 = *(const bf16x8*)&msgB[(w*32 + cl)      * SB + kt*32 + quad*8];
    bf16x8 af1 = *(const bf16x8*)&msgB[(w*32 + 16 + cl) * SB + kt*32 + quad*8];
#pragma unroll
    for (int nt = 0; nt < NT; ++nt) {
      bf16x8 bfr = *(const bf16x8*)&WbT[(size_t)(nt*16 + cl) * CMID + kt*32 + quad*8];
      acc2[0][nt] = __builtin_amdgcn_mfma_f32_16x16x32_bf16(af0, bfr, acc2[0][nt], 0, 0, 0);
      acc2[1][nt] = __builtin_amdgcn_mfma_f32_16x16x32_bf16(af1, bfr, acc2[1][nt], 0, 0, 0);
    }
  }

#pragma unroll
  for (int mt = 0; mt < 2; ++mt) {
    int node = node0 + w*2 + mt;
#pragma unroll
    for (int nt = 0; nt < NT; ++nt) {
      float m = fmaxf(fmaxf(acc2[mt][nt][0], acc2[mt][nt][1]),
                      fmaxf(acc2[mt][nt][2], acc2[mt][nt][3]));
      m = fmaxf(m, __shfl_xor(m, 16, 64));
      m = fmaxf(m, __shfl_xor(m, 32, 64));
      float v = fmaxf(m + bbf[nt*16 + cl], 0.0f);
      if (quad == 0) {
        size_t oi = (size_t)node * CMID + nt*16 + cl;
        if (xoutb) xoutb[oi] = f2bfb(v);
        stv(bout, out_off + oi, mode, v);
      }
    }
  }
}

// ---------------------------------------------------------------------------
extern "C" void kernel_launch(void* const* d_in, const int* in_sizes, int n_in,
                              void* d_out, int out_size, void* d_ws, size_t ws_size,
                              hipStream_t stream) {
  (void)n_in; (void)ws_size; (void)in_sizes;
  int n = out_size / 256;
  if (n <= 0 || (n & 255)) n = 16384;

  float* ws = (float*)d_ws;
  int*    flag    = (int*)ws;                                       // 16
  float4* pos4    = (float4*)(ws + 16);                             // 4n
  float*  h0      = ws + 16 + (size_t)4*n;                          // 6n
  int*    nbr     = (int*)(ws + 16 + (size_t)10*n);                 // 16n
  unsigned short* h1b = (unsigned short*)(ws + 16 + (size_t)26*n);  // 32n
  unsigned short* h2b = (unsigned short*)(ws + 16 + (size_t)58*n);  // 32n
  float*  vbuf    = ws + 16 + (size_t)90*n;                         // 1024
  unsigned short* wtbuf = (unsigned short*)(vbuf + 1024);

  const int vsz[12] = {64,64,64,64, 64,64,64,64, 128,128,128,128};
  const int vsrc[12] = {3,4,5,7, 9,10,11,13, 15,16,17,19};
  CvtArgs ca;
  float* vptr[12];
  {
    int off = 0;
    for (int t = 0; t < 12; ++t) {
      ca.e[t].src = d_in[vsrc[t]];
      ca.e[t].dst = vbuf + off;
      ca.e[t].n   = vsz[t];
      vptr[t] = vbuf + off;
      off += vsz[t];
    }
  }
  const int wK[6]    = {9, 64, 67, 64, 67, 128};
  const int wN[6]    = {64, 64, 64, 64, 128, 128};
  const int wKp[6]   = {32, 64, 96, 64, 96, 128};
  const int wsrc[6]  = {2, 6, 8, 12, 14, 18};
  WArgs wa;
  unsigned short* wptr[6];
  {
    int off = 0;
    for (int t = 0; t < 6; ++t) {
      wa.e[t].src  = d_in[wsrc[t]];
      wa.e[t].dst  = wtbuf + off;
      wa.e[t].K    = wK[t];
      wa.e[t].N    = wN[t];
      wa.e[t].Kpad = wKp[t];
      wptr[t] = wtbuf + off;
      off += wN[t] * wKp[t];
    }
  }

  setup_kernel<<<n/256 + 7, 256, 0, stream>>>(
      d_in[0], d_in[1], wa, ca, flag, pos4, h0, n);
  knn4_kernel<<<n/KNN_WPB, KNN_TPB, 0, stream>>>(pos4, nbr, n);

  // <CIN, CMID, KT1, NT, KT2>
  conv_mfma5_kernel<6, 64, 1, 4, 2><<<n/8, 256, 0, stream>>>(
      h0, (const unsigned short*)nullptr, pos4, nbr, flag, wptr[0], wptr[1],
      vptr[0], vptr[1], vptr[2], vptr[3], h1b, d_out, (size_t)0);
  conv_mfma5_kernel<64, 64, 3, 4, 2><<<n/8, 256, 0, stream>>>(
      (const float*)nullptr, h1b, pos4, nbr, flag, wptr[2], wptr[3],
      vptr[4], vptr[5], vptr[6], vptr[7], h2b, d_out, (size_t)n*64);
  conv_mfma5_kernel<64, 128, 3, 8, 4><<<n/8, 256, 0, stream>>>(
      (const float*)nullptr, h2b, pos4, nbr, flag, wptr[4], wptr[5],
      vptr[8], vptr[9], vptr[10], vptr[11],
      (unsigned short*)nullptr, d_out, (size_t)n*128);
}

// Round 15
// 369.077 us; speedup vs baseline: 2.1837x; 1.0070x over previous
//
#include <hip/hip_runtime.h>
#include <hip/hip_bf16.h>
#include <stdint.h>

typedef unsigned long long u64;
typedef unsigned int u32;
typedef __attribute__((ext_vector_type(8))) short bf16x8;
typedef __attribute__((ext_vector_type(8))) unsigned short u16x8;
typedef __attribute__((ext_vector_type(4))) float f32x4;

__device__ __forceinline__ float ldv(const void* p, size_t idx, int mode) {
  return mode ? __bfloat162float(((const __hip_bfloat16*)p)[idx])
              : ((const float*)p)[idx];
}
__device__ __forceinline__ void stv(void* p, size_t idx, int mode, float v) {
  if (mode) ((__hip_bfloat16*)p)[idx] = __float2bfloat16(v);
  else      ((float*)p)[idx] = v;
}
__device__ __forceinline__ unsigned short f2bfb(float f) {  // RNE f32->bf16 bits
  u32 u = __float_as_uint(f);
  u32 r = u + 0x7fffu + ((u >> 16) & 1u);
  return (unsigned short)(r >> 16);
}
__device__ __forceinline__ float bfb2f(unsigned short b) {
  return __uint_as_float((u32)b << 16);
}
__device__ __forceinline__ u64 shfl64(u64 v, int src) {
  int lo = __shfl((int)(u32)(v & 0xffffffffu), src, 64);
  int hi = __shfl((int)(u32)(v >> 32), src, 64);
  return ((u64)(u32)hi << 32) | (u32)lo;
}
__device__ __forceinline__ u64 shflxor64(u64 v, int m) {
  int lo = __shfl_xor((int)(u32)(v & 0xffffffffu), m, 64);
  int hi = __shfl_xor((int)(u32)(v >> 32), m, 64);
  return ((u64)(u32)hi << 32) | (u32)lo;
}
__device__ __forceinline__ u64 shfl64w16(u64 v, int src) {  // width-16 shfl
  int lo = __shfl((int)(u32)(v & 0xffffffffu), src, 16);
  int hi = __shfl((int)(u32)(v >> 32), src, 16);
  return ((u64)(u32)hi << 32) | (u32)lo;
}

__global__ void PointNetSimple_61409442398998_kernel() {}

// ---------------------------------------------------------------------------
// setup: dtype-detect + weight transpose/convert + vector cvt + prep.
// ---------------------------------------------------------------------------
struct CvtEnt { const void* src; float* dst; int n; };
struct CvtArgs { CvtEnt e[12]; };
struct WEnt { const void* src; unsigned short* dst; int K, N, Kpad; };
struct WArgs { WEnt e[6]; };

__global__ void setup_kernel(const void* __restrict__ pos,
                             const void* __restrict__ nrm,
                             WArgs wa, CvtArgs ca,
                             int* __restrict__ flag,
                             float4* __restrict__ pos4,
                             float* __restrict__ h0, int n) {
  const unsigned short* u16p = (const unsigned short*)pos;
  int cnt = 0;
  for (int k = 0; k < 32; ++k) {
    int e = (u16p[k] >> 7) & 0xff;
    if (e >= 110 && e <= 140) cnt++;
  }
  const int mode = (cnt >= 26) ? 1 : 0;

  const int nprep = n >> 8;
  const int b = blockIdx.x;
  if (b < nprep) {
    int i = b * 256 + threadIdx.x;
    float x = ldv(pos, 3*(size_t)i+0, mode);
    float y = ldv(pos, 3*(size_t)i+1, mode);
    float z = ldv(pos, 3*(size_t)i+2, mode);
    pos4[i] = make_float4(x, y, z, x*x + y*y + z*z);
    h0[6*(size_t)i+0] = x; h0[6*(size_t)i+1] = y; h0[6*(size_t)i+2] = z;
    h0[6*(size_t)i+3] = ldv(nrm, 3*(size_t)i+0, mode);
    h0[6*(size_t)i+4] = ldv(nrm, 3*(size_t)i+1, mode);
    h0[6*(size_t)i+5] = ldv(nrm, 3*(size_t)i+2, mode);
  } else {
    int r = b - nprep;
    if (r < 6) {
      WEnt ent = wa.e[r];
      for (int t = threadIdx.x; t < ent.N * ent.Kpad; t += blockDim.x) {
        int nn = t / ent.Kpad;
        int k  = t - nn * ent.Kpad;
        float v = (k < ent.K) ? ldv(ent.src, (size_t)k * ent.N + nn, mode) : 0.0f;
        ent.dst[t] = f2bfb(v);
      }
      if (r == 0 && threadIdx.x == 0) flag[0] = mode;
    } else {
      for (int t2 = 0; t2 < 12; ++t2) {
        CvtEnt ent = ca.e[t2];
        for (int t = threadIdx.x; t < ent.n; t += blockDim.x)
          ent.dst[t] = ldv(ent.src, t, mode);
      }
    }
  }
}

// ---------------------------------------------------------------------------
// knn v4 (proven ~169 us): wave-per-target, streaming LDS chunks, mbcnt
// compaction + exact bitonic flush. u64 keys = exact lax.top_k order.
// d2 expression verbatim (boundary-rounding frozen).
// ---------------------------------------------------------------------------
#define KNN_TPB 512
#define KNN_WPB 8
#define KCH 1024

__device__ __forceinline__ void knn_flush(u64* __restrict__ wbuf, int& cnt,
                                          u64& val, u64& t15, float& th,
                                          int lane) {
  u64 cand = (lane < cnt) ? wbuf[lane] : ~0ull;
#pragma unroll
  for (int k = 2; k <= 64; k <<= 1) {
#pragma unroll
    for (int j = k >> 1; j > 0; j >>= 1) {
      u64 other = shflxor64(cand, j);
      bool up    = ((lane & k) == 0) || (k == 64);
      bool lower = ((lane & j) == 0);
      bool keepMin = (up == lower);
      u64 mn = cand < other ? cand : other;
      u64 mx = cand < other ? other : cand;
      cand = keepMin ? mn : mx;
    }
  }
  u64 rev = shfl64w16(cand, 15 - (lane & 15));
  u64 lo = val < rev ? val : rev;
#pragma unroll
  for (int j = 8; j > 0; j >>= 1) {
    u64 other = shflxor64(lo, j);
    bool lower = ((lane & j) == 0);
    u64 mn = lo < other ? lo : other;
    u64 mx = lo < other ? other : lo;
    lo = lower ? mn : mx;
  }
  val = (lane < 16) ? lo : ~0ull;
  t15 = shfl64(val, 15);
  th = __uint_as_float((u32)(t15 >> 32));
  cnt = 0;
}

__global__ __launch_bounds__(KNN_TPB) void knn4_kernel(
    const float4* __restrict__ pos4, int* __restrict__ nbr, int n) {
  __shared__ float4 sp[2][KCH];
  __shared__ u64 buf[KNN_WPB][72];
  const int tid  = threadIdx.x;
  const int lane = tid & 63;
  const int wid  = tid >> 6;
  const int i    = blockIdx.x * KNN_WPB + wid;
  const float4 pi = pos4[i];
  u64* wbuf = &buf[wid][0];

  u64 val = ~0ull;
  u64 t15 = ~0ull;
  float th = 3.4e38f;
  int cnt = 0;

  for (int t = tid; t < KCH; t += KNN_TPB) sp[0][t] = pos4[t];
  __syncthreads();

  const int nch = n / KCH;
  for (int c = 0; c < nch; ++c) {
    const int cur = c & 1;
    float4 pre0, pre1;
    const bool more = (c + 1 < nch);
    if (more) {
      pre0 = pos4[(size_t)(c+1)*KCH + tid];
      pre1 = pos4[(size_t)(c+1)*KCH + KNN_TPB + tid];
    }
#pragma unroll 2
    for (int t = 0; t < KCH; t += 64) {
      float4 a = sp[cur][t + lane];
      float d2 = (pi.w + a.w) - 2.0f*(pi.x*a.x + pi.y*a.y + pi.z*a.z);
      d2 = fmaxf(d2, 0.0f);
      bool pass = (d2 <= th);
      u64 bal = __ballot(pass);
      if (bal) {
        int pc = __popcll(bal);
        if (cnt + pc > 64) knn_flush(wbuf, cnt, val, t15, th, lane);
        u32 mb = __builtin_amdgcn_mbcnt_lo((u32)bal, 0u);
        mb = __builtin_amdgcn_mbcnt_hi((u32)(bal >> 32), mb);
        if (pass)
          wbuf[cnt + mb] = ((u64)__float_as_uint(d2) << 32) | (u32)(c*KCH + t + lane);
        cnt += pc;
      }
    }
    if (more) {
      sp[cur^1][tid] = pre0;
      sp[cur^1][KNN_TPB + tid] = pre1;
    }
    __syncthreads();
  }
  knn_flush(wbuf, cnt, val, t15, th, lane);
  if (lane < 16) nbr[(size_t)i*16 + lane] = (int)(val & 0xffffffffu);
}

// ---------------------------------------------------------------------------
// MFMA conv v6: REGISTER-LIVENESS restructure. GEMM1 is computed ONE N-tile
// at a time (a1[2] = 8 VGPR) and immediately bias+bf16+GN'd into msgB —
// acc1[2][NT] (64 VGPR in conv3) never exists. Peak live ~= afr(24) + a1(8)
// + acc2(64) + temps < 128 => no scratch spills under launch_bounds(256,4).
// Numerics bit-identical to v5 (same ops, same per-tile order, loop-jammed).
// Zero __syncthreads (per-wave LDS bands + same-wave DS FIFO ordering).
// ---------------------------------------------------------------------------
template<int CIN, int CMID, int KT1, int NT, int KT2>
__global__ __launch_bounds__(256, 4) void conv_mfma6_kernel(
    const float* __restrict__ xf,             // [N,6] fp32 (CIN==6)
    const unsigned short* __restrict__ xb,    // [N,64] bf16 (CIN==64)
    const float4* __restrict__ pos4,
    const int* __restrict__ nbr,
    const int* __restrict__ flag,
    const unsigned short* __restrict__ WaT,   // [CMID][K1PAD] bf16
    const unsigned short* __restrict__ WbT,   // [CMID][CMID]  bf16
    const float* __restrict__ baf,
    const float* __restrict__ gmf,
    const float* __restrict__ btf,
    const float* __restrict__ bbf,
    unsigned short* __restrict__ xoutb,       // [N,CMID] bf16 ws (may be null)
    void* __restrict__ bout, size_t out_off)
{
  constexpr int K1PAD = KT1 * 32;
  constexpr int SB = CMID + 8;

  __shared__ unsigned short msgB[128 * SB];

  const int tid  = threadIdx.x;
  const int lane = tid & 63;
  const int w    = tid >> 6;
  const int quad = lane >> 4;
  const int cl   = lane & 15;
  const int node0 = blockIdx.x * 8;
  const int mode = flag[0];

  bf16x8 afr[2][KT1];
#pragma unroll
  for (int mt = 0; mt < 2; ++mt) {
    const int node = node0 + w*2 + mt;
    const int j = nbr[(size_t)node*16 + cl];
    const float4 pin = pos4[node];
    const float4 pj = pos4[j];
    const float rx = pj.x - pin.x, ry = pj.y - pin.y, rz = pj.z - pin.z;
    if constexpr (CIN == 64) {
#pragma unroll
      for (int kt = 0; kt < 2; ++kt)
        afr[mt][kt] = *(const bf16x8*)&xb[(size_t)j*64 + kt*32 + quad*8];
      unsigned short o[8] = {0,0,0,0,0,0,0,0};
      if (quad == 0) { o[0] = f2bfb(rx); o[1] = f2bfb(ry); o[2] = f2bfb(rz); }
      afr[mt][KT1-1] = *(bf16x8*)o;
    } else {  // CIN == 6
      unsigned short o[8] = {0,0,0,0,0,0,0,0};
      if (quad == 0) {
        const float* p = &xf[(size_t)j*6];
        o[0] = f2bfb(p[0]); o[1] = f2bfb(p[1]); o[2] = f2bfb(p[2]);
        o[3] = f2bfb(p[3]); o[4] = f2bfb(p[4]); o[5] = f2bfb(p[5]);
        o[6] = f2bfb(rx);   o[7] = f2bfb(ry);
      } else if (quad == 1) {
        o[0] = f2bfb(rz);
      }
      afr[mt][0] = *(bf16x8*)o;
    }
  }

  // ---- GEMM1 + bias + GN, ONE tile at a time (a1 live = 8 VGPR) ----
  const int grow = lane >> 1, ggl = lane & 1;    // GN thread mapping
#pragma unroll
  for (int nt = 0; nt < NT; ++nt) {
    f32x4 a1[2];
    a1[0] = (f32x4){0.f, 0.f, 0.f, 0.f};
    a1[1] = (f32x4){0.f, 0.f, 0.f, 0.f};
#pragma unroll
    for (int kt = 0; kt < KT1; ++kt) {
      bf16x8 bfr = *(const bf16x8*)&WaT[(size_t)(nt*16 + cl) * K1PAD + kt*32 + quad*8];
      a1[0] = __builtin_amdgcn_mfma_f32_16x16x32_bf16(afr[0][kt], bfr, a1[0], 0, 0, 0);
      a1[1] = __builtin_amdgcn_mfma_f32_16x16x32_bf16(afr[1][kt], bfr, a1[1], 0, 0, 0);
    }
    float bac = baf[nt*16 + cl];
#pragma unroll
    for (int mt = 0; mt < 2; ++mt)
#pragma unroll
      for (int reg = 0; reg < 4; ++reg)
        msgB[(w*32 + mt*16 + quad*4 + reg) * SB + nt*16 + cl] =
            f2bfb(a1[mt][reg] + bac);
    asm volatile("" ::: "memory");   // same-wave DS FIFO: write < read
    {
      const int cb = nt*16 + ggl*8;
      unsigned short* p = &msgB[(w*32 + grow) * SB + cb];
      u16x8 hv = *(const u16x8*)p;
      float vv[8];
#pragma unroll
      for (int e = 0; e < 8; ++e) vv[e] = bfb2f(hv[e]);
      float s = 0.f, q = 0.f;
#pragma unroll
      for (int e = 0; e < 8; ++e) { s += vv[e]; q += vv[e]*vv[e]; }
      float mu = s * 0.125f;
      float var = q * 0.125f - mu * mu;
      float inv = rsqrtf(fmaxf(var, 0.0f) + 1e-5f);
      unsigned short o[8];
#pragma unroll
      for (int e = 0; e < 8; ++e) {
        float t = (vv[e] - mu) * inv * gmf[cb+e] + btf[cb+e];
        o[e] = f2bfb(fmaxf(t, 0.0f));
      }
      *(bf16x8*)p = *(bf16x8*)o;
    }
    asm volatile("" ::: "memory");
  }

  // ---- GEMM2 (A from this wave's msgB band only) ----
  f32x4 acc2[2][NT];
#pragma unroll
  for (int mt = 0; mt < 2; ++mt)
#pragma unroll
    for (int nt = 0; nt < NT; ++nt) acc2[mt][nt] = (f32x4){0.f, 0.f, 0.f, 0.f};
#pragma unroll
  for (int kt = 0; kt < KT2; ++kt) {
    bf16x8 af0 = *(const bf16x8*)&msgB[(w*32 + cl)      * SB + kt*32 + quad*8];
    bf16x8 af1 = *(const bf16x8*)&msgB[(w*32 + 16 + cl) * SB + kt*32 + quad*8];
#pragma unroll
    for (int nt = 0; nt < NT; ++nt) {
      bf16x8 bfr = *(const bf16x8*)&WbT[(size_t)(nt*16 + cl) * CMID + kt*32 + quad*8];
      acc2[0][nt] = __builtin_amdgcn_mfma_f32_16x16x32_bf16(af0, bfr, acc2[0][nt], 0, 0, 0);
      acc2[1][nt] = __builtin_amdgcn_mfma_f32_16x16x32_bf16(af1, bfr, acc2[1][nt], 0, 0, 0);
    }
  }

#pragma unroll
  for (int mt = 0; mt < 2; ++mt) {
    int node = node0 + w*2 + mt;
#pragma unroll
    for (int nt = 0; nt < NT; ++nt) {
      float m = fmaxf(fmaxf(acc2[mt][nt][0], acc2[mt][nt][1]),
                      fmaxf(acc2[mt][nt][2], acc2[mt][nt][3]));
      m = fmaxf(m, __shfl_xor(m, 16, 64));
      m = fmaxf(m, __shfl_xor(m, 32, 64));
      float v = fmaxf(m + bbf[nt*16 + cl], 0.0f);
      if (quad == 0) {
        size_t oi = (size_t)node * CMID + nt*16 + cl;
        if (xoutb) xoutb[oi] = f2bfb(v);
        stv(bout, out_off + oi, mode, v);
      }
    }
  }
}

// ---------------------------------------------------------------------------
extern "C" void kernel_launch(void* const* d_in, const int* in_sizes, int n_in,
                              void* d_out, int out_size, void* d_ws, size_t ws_size,
                              hipStream_t stream) {
  (void)n_in; (void)ws_size; (void)in_sizes;
  int n = out_size / 256;
  if (n <= 0 || (n & 255)) n = 16384;

  float* ws = (float*)d_ws;
  int*    flag    = (int*)ws;                                       // 16
  float4* pos4    = (float4*)(ws + 16);                             // 4n
  float*  h0      = ws + 16 + (size_t)4*n;                          // 6n
  int*    nbr     = (int*)(ws + 16 + (size_t)10*n);                 // 16n
  unsigned short* h1b = (unsigned short*)(ws + 16 + (size_t)26*n);  // 32n
  unsigned short* h2b = (unsigned short*)(ws + 16 + (size_t)58*n);  // 32n
  float*  vbuf    = ws + 16 + (size_t)90*n;                         // 1024
  unsigned short* wtbuf = (unsigned short*)(vbuf + 1024);

  const int vsz[12] = {64,64,64,64, 64,64,64,64, 128,128,128,128};
  const int vsrc[12] = {3,4,5,7, 9,10,11,13, 15,16,17,19};
  CvtArgs ca;
  float* vptr[12];
  {
    int off = 0;
    for (int t = 0; t < 12; ++t) {
      ca.e[t].src = d_in[vsrc[t]];
      ca.e[t].dst = vbuf + off;
      ca.e[t].n   = vsz[t];
      vptr[t] = vbuf + off;
      off += vsz[t];
    }
  }
  const int wK[6]    = {9, 64, 67, 64, 67, 128};
  const int wN[6]    = {64, 64, 64, 64, 128, 128};
  const int wKp[6]   = {32, 64, 96, 64, 96, 128};
  const int wsrc[6]  = {2, 6, 8, 12, 14, 18};
  WArgs wa;
  unsigned short* wptr[6];
  {
    int off = 0;
    for (int t = 0; t < 6; ++t) {
      wa.e[t].src  = d_in[wsrc[t]];
      wa.e[t].dst  = wtbuf + off;
      wa.e[t].K    = wK[t];
      wa.e[t].N    = wN[t];
      wa.e[t].Kpad = wKp[t];
      wptr[t] = wtbuf + off;
      off += wN[t] * wKp[t];
    }
  }

  setup_kernel<<<n/256 + 7, 256, 0, stream>>>(
      d_in[0], d_in[1], wa, ca, flag, pos4, h0, n);
  knn4_kernel<<<n/KNN_WPB, KNN_TPB, 0, stream>>>(pos4, nbr, n);

  // <CIN, CMID, KT1, NT, KT2>
  conv_mfma6_kernel<6, 64, 1, 4, 2><<<n/8, 256, 0, stream>>>(
      h0, (const unsigned short*)nullptr, pos4, nbr, flag, wptr[0], wptr[1],
      vptr[0], vptr[1], vptr[2], vptr[3], h1b, d_out, (size_t)0);
  conv_mfma6_kernel<64, 64, 3, 4, 2><<<n/8, 256, 0, stream>>>(
      (const float*)nullptr, h1b, pos4, nbr, flag, wptr[2], wptr[3],
      vptr[4], vptr[5], vptr[6], vptr[7], h2b, d_out, (size_t)n*64);
  conv_mfma6_kernel<64, 128, 3, 8, 4><<<n/8, 256, 0, stream>>>(
      (const float*)nullptr, h2b, pos4, nbr, flag, wptr[4], wptr[5],
      vptr[8], vptr[9], vptr[10], vptr[11],
      (unsigned short*)nullptr, d_out, (size_t)n*128);
}